// Round 12
// baseline (343.982 us; speedup 1.0000x reference)
//
#include <hip/hip_runtime.h>
#include <math.h>

#define DEVI __device__ __forceinline__

typedef unsigned int u32;
typedef unsigned short u16;
typedef __attribute__((ext_vector_type(8))) __bf16 bf16x8;
typedef __attribute__((ext_vector_type(8))) u16 u16x8;
typedef __attribute__((ext_vector_type(4))) float f32x4;

DEVI float rcp_f(float x) { return __builtin_amdgcn_rcpf(x); }
DEVI float silu_f(float x) { return x * rcp_f(1.0f + __expf(-x)); }
// fast softplus: max(x,0) + log(1+exp(-|x|)); abs err < 1e-7.
DEVI float softplus_f(float x) {
  return fmaxf(x, 0.0f) + __logf(1.0f + __expf(-fabsf(x)));
}

DEVI u32 bf16_rne(float f) {
  u32 u = __float_as_uint(f);
  return (u + 0x7fffu + ((u >> 16) & 1u)) >> 16;
}
// split-plane store: H plane at [0,PN), L plane at [PN,2PN).
DEVI void split_store(u16* __restrict__ p, long idx, long PN, float v) {
  const u32 h = bf16_rne(v);
  const float hf = __uint_as_float(h << 16);
  p[idx] = (u16)h;
  p[PN + idx] = (u16)bf16_rne(v - hf);
}

DEVI void load16(float* r, const float* __restrict__ p) {
  const float4* q = (const float4*)p;
  float4 a = q[0], b = q[1], c = q[2], d = q[3];
  r[0]=a.x; r[1]=a.y; r[2]=a.z; r[3]=a.w;
  r[4]=b.x; r[5]=b.y; r[6]=b.z; r[7]=b.w;
  r[8]=c.x; r[9]=c.y; r[10]=c.z; r[11]=c.w;
  r[12]=d.x; r[13]=d.y; r[14]=d.z; r[15]=d.w;
}
DEVI void store16(float* __restrict__ p, const float* r) {
  float4* q = (float4*)p;
  q[0] = make_float4(r[0],r[1],r[2],r[3]);
  q[1] = make_float4(r[4],r[5],r[6],r[7]);
  q[2] = make_float4(r[8],r[9],r[10],r[11]);
  q[3] = make_float4(r[12],r[13],r[14],r[15]);
}
DEVI void load8(float* r, const float* __restrict__ p) {
  const float4* q = (const float4*)p;
  float4 a = q[0], b = q[1];
  r[0]=a.x; r[1]=a.y; r[2]=a.z; r[3]=a.w;
  r[4]=b.x; r[5]=b.y; r[6]=b.z; r[7]=b.w;
}

// ---------------------------------------------------------------------------
// Weight prep: fp32 -> split-plane bf16 hi/lo. Region: [H (N u16)][L (N u16)].
// ---------------------------------------------------------------------------
constexpr int WN1 = 32768, WNO1 = 16384, WNL = 32768, WN2 = 131072, WNO2 = 65536;
constexpr int WOFF1 = 0, WOFFO1 = 32768, WOFFL = 49152, WOFF2 = 81920, WOFFO2 = 212992;
constexpr int WTOT = 278528;

__global__ __launch_bounds__(256) void wprep_kernel(
    const float* __restrict__ w1, const float* __restrict__ wo1,
    const float* __restrict__ wl, const float* __restrict__ w2,
    const float* __restrict__ wo2, u16* __restrict__ dst)
{
  int i = blockIdx.x * 256 + threadIdx.x;
  float v;
  long rb, rn;
  if (i < WOFFO1)       { v = w1[i];            rb = WOFF1;  rn = WN1; }
  else if (i < WOFFL)   { v = wo1[i - WOFFO1];  rb = WOFFO1; rn = WNO1; }
  else if (i < WOFF2)   { v = wl[i - WOFFL];    rb = WOFFL;  rn = WNL; }
  else if (i < WOFFO2)  { v = w2[i - WOFF2];    rb = WOFF2;  rn = WN2; }
  else                  { v = wo2[i - WOFFO2];  rb = WOFFO2; rn = WNO2; }
  split_store(dst + 2 * rb, i - rb, rn, v);
}

// ---------------------------------------------------------------------------
// Transpose: fp32 (b, C, L) -> split-plane bf16 (b*L, C); NE = total elems.
// ---------------------------------------------------------------------------
__global__ __launch_bounds__(256) void tpose_kernel(
    const float* __restrict__ in, u16* __restrict__ out, long NE, int C, int L)
{
  __shared__ float t[32][33];
  const int l0 = blockIdx.x * 32, c0 = blockIdx.y * 32, b = blockIdx.z;
  const int tx = threadIdx.x & 31, ty = threadIdx.x >> 5;
  const float* src = in + ((long)b * C + c0) * L + l0;
  #pragma unroll
  for (int r = 0; r < 32; r += 8) t[ty + r][tx] = src[(long)(ty + r) * L + tx];
  __syncthreads();
  const long dbase = ((long)b * L + l0) * C + c0;
  #pragma unroll
  for (int r = 0; r < 32; r += 8)
    split_store(out, dbase + (long)(ty + r) * C + tx, NE, t[tx][ty + r]);
}

// ---------------------------------------------------------------------------
// MFMA GEMM (bf16x3 split): C[m,n] = sum_k A[m,k]*W[n,k] (+bias)
// v13: XOR chunk-swizzle REMOVED. Row stride 40 u16 = 20 banks; base bank
// = 4*((5*row) mod 8) is itself a permutation over the 8 four-bank slots,
// so the natural chunk layout is uniform. The old XOR (designed for a
// 16-bank stride) collapsed writes AND reads onto even slots (2x conflict,
// the constant 6.29M SQ_LDS_BANK_CONFLICT). Register-prefetch dbuf + XCD
// swizzle kept from v10.
// ---------------------------------------------------------------------------
template<int EPI>
__global__ __launch_bounds__(256) void mgemm_kernel(
    const u16* __restrict__ Ap, long AN, const u16* __restrict__ Wp, long WN,
    const float* __restrict__ bias, int M, int N, int K,
    float* __restrict__ out0, float* __restrict__ out1,
    u16* __restrict__ outp, long PN, int di, int L)
{
  __shared__ u16 Ah[128][40], Al[128][40], Bh[128][40], Bl[128][40];
  const int tid = threadIdx.x;
  const int wid = tid >> 6, lane = tid & 63;
  const int lm = lane & 15, lq = lane >> 4;

  // XCD-chunked swizzle
  int bx = blockIdx.x, by = blockIdx.y;
  {
    const int nwg = gridDim.x * gridDim.y;
    if ((nwg & 7) == 0) {
      int flat = by * gridDim.x + bx;
      const int q = nwg >> 3;
      flat = (flat & 7) * q + (flat >> 3);
      bx = flat % gridDim.x;
      by = flat / gridDim.x;
    }
  }
  const int m0 = by * 128, n0 = bx * 128;
  const int wr = (wid >> 1) * 64, wn = (wid & 1) * 64;
  const int sr = tid >> 1;
  const int sc = (tid & 1) * 2;
  const int o0 = (sc + 0) * 8;        // natural chunk position (no XOR)
  const int o1 = (sc + 1) * 8;

  f32x4 acc[4][4];
  #pragma unroll
  for (int i = 0; i < 4; ++i)
    #pragma unroll
    for (int j = 0; j < 4; ++j)
      #pragma unroll
      for (int r = 0; r < 4; ++r) acc[i][j][r] = 0.0f;

  const u16* gaH = Ap + (long)(m0 + sr) * K + sc * 8;
  const u16* gaL = gaH + AN;
  const u16* gbH = Wp + (long)(n0 + sr) * K + sc * 8;
  const u16* gbL = gbH + WN;
  const int co = lq * 8;              // natural chunk read (no XOR)
  const int nt = K >> 5;

  // preload tile 0 into registers
  uint4 ah0 = *(const uint4*)(gaH);
  uint4 ah1 = *(const uint4*)(gaH + 8);
  uint4 al0 = *(const uint4*)(gaL);
  uint4 al1 = *(const uint4*)(gaL + 8);
  uint4 bh0 = *(const uint4*)(gbH);
  uint4 bh1 = *(const uint4*)(gbH + 8);
  uint4 bl0 = *(const uint4*)(gbL);
  uint4 bl1 = *(const uint4*)(gbL + 8);

  for (int kt = 0; kt < nt; ++kt) {
    *(uint4*)&Ah[sr][o0] = ah0; *(uint4*)&Ah[sr][o1] = ah1;
    *(uint4*)&Al[sr][o0] = al0; *(uint4*)&Al[sr][o1] = al1;
    *(uint4*)&Bh[sr][o0] = bh0; *(uint4*)&Bh[sr][o1] = bh1;
    *(uint4*)&Bl[sr][o0] = bl0; *(uint4*)&Bl[sr][o1] = bl1;
    __syncthreads();

    if (kt + 1 < nt) {
      const int k0 = (kt + 1) << 5;
      ah0 = *(const uint4*)(gaH + k0);
      ah1 = *(const uint4*)(gaH + k0 + 8);
      al0 = *(const uint4*)(gaL + k0);
      al1 = *(const uint4*)(gaL + k0 + 8);
      bh0 = *(const uint4*)(gbH + k0);
      bh1 = *(const uint4*)(gbH + k0 + 8);
      bl0 = *(const uint4*)(gbL + k0);
      bl1 = *(const uint4*)(gbL + k0 + 8);
    }

    bf16x8 fah[4], fal[4];
    #pragma unroll
    for (int i = 0; i < 4; ++i) {
      fah[i] = *(const bf16x8*)&Ah[wr + 16 * i + lm][co];
      fal[i] = *(const bf16x8*)&Al[wr + 16 * i + lm][co];
    }
    #pragma unroll
    for (int j = 0; j < 4; ++j) {
      bf16x8 fbh = *(const bf16x8*)&Bh[wn + 16 * j + lm][co];
      bf16x8 fbl = *(const bf16x8*)&Bl[wn + 16 * j + lm][co];
      #pragma unroll
      for (int i = 0; i < 4; ++i) {
        acc[i][j] = __builtin_amdgcn_mfma_f32_16x16x32_bf16(fah[i], fbh, acc[i][j], 0, 0, 0);
        acc[i][j] = __builtin_amdgcn_mfma_f32_16x16x32_bf16(fah[i], fbl, acc[i][j], 0, 0, 0);
        acc[i][j] = __builtin_amdgcn_mfma_f32_16x16x32_bf16(fal[i], fbh, acc[i][j], 0, 0, 0);
      }
    }
    __syncthreads();
  }

  if constexpr (EPI == 0) {
    const int b = m0 >> 12;
    const int lb = (m0 & 4095) + wr;
    #pragma unroll
    for (int j = 0; j < 4; ++j) {
      const int n = n0 + wn + 16 * j + lm;
      const float bv = bias[n];
      float* base = (n < di) ? out0 + ((long)b * di + n) * L
                             : out1 + ((long)b * di + (n - di)) * L;
      #pragma unroll
      for (int i = 0; i < 4; ++i) {
        const int l = lb + 16 * i + lq * 4;
        *(float4*)(base + l) = make_float4(acc[i][j][0] + bv, acc[i][j][1] + bv,
                                           acc[i][j][2] + bv, acc[i][j][3] + bv);
      }
    }
  } else {
    #pragma unroll
    for (int j = 0; j < 4; ++j) {
      const int n = n0 + wn + 16 * j + lm;
      const float bv = bias[n];
      #pragma unroll
      for (int i = 0; i < 4; ++i) {
        const long mg = m0 + wr + 16 * i + lq * 4;
        #pragma unroll
        for (int r = 0; r < 4; ++r)
          split_store(outp, (mg + r) * N + n, PN, silu_f(acc[i][j][r] + bv));
      }
    }
  }
}

// ---------------------------------------------------------------------------
// MFMA GEMM + fused LayerNorm over full width BN. Split-plane A/W.
// v13: XOR chunk-swizzle removed (same bank analysis as mgemm).
// ---------------------------------------------------------------------------
template<int BN, int EPI>
__global__ __launch_bounds__(256) void lgemm_kernel(
    const u16* __restrict__ Ap, long AN, const u16* __restrict__ Wp, long WN,
    const float* __restrict__ lnw, const float* __restrict__ lnb,
    int M, int K, u16* __restrict__ outp, long PN, float* __restrict__ outf, int L)
{
  constexpr int NT = BN / 64;
  __shared__ u16 Ah[64][40], Al[64][40], Bh[BN][40], Bl[BN][40];
  __shared__ float red[4][64];
  __shared__ float muS[64], rsS[64];

  const int tid = threadIdx.x;
  const int wid = tid >> 6, lane = tid & 63;
  const int lm = lane & 15, lq = lane >> 4;
  const int m0 = blockIdx.x * 64;
  const int wn = wid * (BN / 4);
  const int sa_r = tid >> 2, sa_c = tid & 3;
  const int sa_o = sa_c * 8;          // natural chunk position
  const int co = lq * 8;              // natural chunk read

  f32x4 acc[4][NT];
  #pragma unroll
  for (int i = 0; i < 4; ++i)
    #pragma unroll
    for (int j = 0; j < NT; ++j)
      #pragma unroll
      for (int r = 0; r < 4; ++r) acc[i][j][r] = 0.0f;

  const u16* gaH = Ap + (long)(m0 + sa_r) * K + sa_c * 8;
  const u16* gaL = gaH + AN;

  for (int k0 = 0; k0 < K; k0 += 32) {
    uint4 ah = *(const uint4*)(gaH + k0);
    uint4 al = *(const uint4*)(gaL + k0);
    *(uint4*)&Ah[sa_r][sa_o] = ah;
    *(uint4*)&Al[sa_r][sa_o] = al;
    #pragma unroll
    for (int it = 0; it < NT; ++it) {
      const int idx = tid + it * 256;
      const int n = idx >> 2, c = idx & 3;
      const u16* gwH = Wp + (long)n * K + k0 + c * 8;
      uint4 bh = *(const uint4*)gwH;
      uint4 bl = *(const uint4*)(gwH + WN);
      const int o = c * 8;            // natural chunk position
      *(uint4*)&Bh[n][o] = bh;
      *(uint4*)&Bl[n][o] = bl;
    }
    __syncthreads();

    bf16x8 fah[4], fal[4];
    #pragma unroll
    for (int i = 0; i < 4; ++i) {
      fah[i] = *(const bf16x8*)&Ah[16 * i + lm][co];
      fal[i] = *(const bf16x8*)&Al[16 * i + lm][co];
    }
    #pragma unroll
    for (int j = 0; j < NT; ++j) {
      bf16x8 fbh = *(const bf16x8*)&Bh[wn + 16 * j + lm][co];
      bf16x8 fbl = *(const bf16x8*)&Bl[wn + 16 * j + lm][co];
      #pragma unroll
      for (int i = 0; i < 4; ++i) {
        acc[i][j] = __builtin_amdgcn_mfma_f32_16x16x32_bf16(fah[i], fbh, acc[i][j], 0, 0, 0);
        acc[i][j] = __builtin_amdgcn_mfma_f32_16x16x32_bf16(fah[i], fbl, acc[i][j], 0, 0, 0);
        acc[i][j] = __builtin_amdgcn_mfma_f32_16x16x32_bf16(fal[i], fbh, acc[i][j], 0, 0, 0);
      }
    }
    __syncthreads();
  }

  // ---- fused LayerNorm over BN ----
  float part[4][4];
  #pragma unroll
  for (int i = 0; i < 4; ++i)
    #pragma unroll
    for (int r = 0; r < 4; ++r) {
      float s = 0.0f;
      #pragma unroll
      for (int j = 0; j < NT; ++j) s += acc[i][j][r];
      part[i][r] = s;
    }
  #pragma unroll
  for (int off = 1; off < 16; off <<= 1)
    #pragma unroll
    for (int i = 0; i < 4; ++i)
      #pragma unroll
      for (int r = 0; r < 4; ++r) part[i][r] += __shfl_xor(part[i][r], off);
  if (lm == 0) {
    #pragma unroll
    for (int i = 0; i < 4; ++i)
      #pragma unroll
      for (int r = 0; r < 4; ++r) red[wid][16 * i + 4 * lq + r] = part[i][r];
  }
  __syncthreads();
  if (tid < 64)
    muS[tid] = (red[0][tid] + red[1][tid] + red[2][tid] + red[3][tid]) * (1.0f / BN);
  __syncthreads();
  float mu_l[4][4];
  #pragma unroll
  for (int i = 0; i < 4; ++i)
    #pragma unroll
    for (int r = 0; r < 4; ++r) mu_l[i][r] = muS[16 * i + 4 * lq + r];
  #pragma unroll
  for (int i = 0; i < 4; ++i)
    #pragma unroll
    for (int r = 0; r < 4; ++r) {
      float s = 0.0f;
      #pragma unroll
      for (int j = 0; j < NT; ++j) {
        float d = acc[i][j][r] - mu_l[i][r];
        s = fmaf(d, d, s);
      }
      part[i][r] = s;
    }
  #pragma unroll
  for (int off = 1; off < 16; off <<= 1)
    #pragma unroll
    for (int i = 0; i < 4; ++i)
      #pragma unroll
      for (int r = 0; r < 4; ++r) part[i][r] += __shfl_xor(part[i][r], off);
  if (lm == 0) {
    #pragma unroll
    for (int i = 0; i < 4; ++i)
      #pragma unroll
      for (int r = 0; r < 4; ++r) red[wid][16 * i + 4 * lq + r] = part[i][r];
  }
  __syncthreads();
  if (tid < 64)
    rsS[tid] = rsqrtf((red[0][tid] + red[1][tid] + red[2][tid] + red[3][tid]) * (1.0f / BN)
                      + 1e-5f);
  __syncthreads();
  float rs_l[4][4];
  #pragma unroll
  for (int i = 0; i < 4; ++i)
    #pragma unroll
    for (int r = 0; r < 4; ++r) rs_l[i][r] = rsS[16 * i + 4 * lq + r];

  if constexpr (EPI == 2) {
    #pragma unroll
    for (int j = 0; j < NT; ++j) {
      const int n = wn + 16 * j + lm;
      const float g = lnw[n], bb = lnb[n];
      #pragma unroll
      for (int i = 0; i < 4; ++i) {
        #pragma unroll
        for (int r = 0; r < 4; ++r) {
          const long mg = m0 + 16 * i + 4 * lq + r;
          split_store(outp, mg * BN + n, PN,
                      (acc[i][j][r] - mu_l[i][r]) * rs_l[i][r] * g + bb);
        }
      }
    }
  } else {
    const int b = m0 >> 12;
    const int lb = m0 & 4095;
    #pragma unroll
    for (int j = 0; j < NT; ++j) {
      const int n = wn + 16 * j + lm;
      const float g = lnw[n], bb = lnb[n];
      #pragma unroll
      for (int i = 0; i < 4; ++i) {
        const int l = lb + 16 * i + 4 * lq;
        float4 v;
        v.x = (acc[i][j][0] - mu_l[i][0]) * rs_l[i][0] * g + bb;
        v.y = (acc[i][j][1] - mu_l[i][1]) * rs_l[i][1] * g + bb;
        v.z = (acc[i][j][2] - mu_l[i][2]) * rs_l[i][2] * g + bb;
        v.w = (acc[i][j][3] - mu_l[i][3]) * rs_l[i][3] * g + bb;
        *(float4*)(outf + ((long)b * BN + n) * L + l) = v;
      }
    }
  }
}

// ---------------------------------------------------------------------------
// Projection: conv(4)+silu (into transposed/swizzled LDS) -> xds/bc.
// v12: wx staged into LDS once per block; all 256 threads conv.
// ---------------------------------------------------------------------------
template<int DI, int R>
__global__ __launch_bounds__(256) void proj_kernel(
    const float* __restrict__ xcpre_t,
    const float* __restrict__ cw, const float* __restrict__ cb,
    const float* __restrict__ wx,
    float* __restrict__ xds_g, float* __restrict__ bc_t, int L)
{
  constexpr int LT = 16;
  constexpr int NP = R + 4;
  constexpr int NC = DI / 4;
  constexpr int NG = 256 / DI;         // 2 for DI=128, 1 for DI=256
  constexpr int PP = LT / NG;          // positions per thread: 8 or 16
  __shared__ float xcT[LT][DI];        // [pos][rot-swizzled ch]
  __shared__ float wxs[NP][DI];        // staged weights

  const int tid = threadIdx.x;
  const int l0 = blockIdx.x * LT;
  const int bz = blockIdx.y;

  // stage wx -> LDS (float4, coalesced; NP*NC float4s)
  for (int idx = tid; idx < NP * NC; idx += 256)
    ((float4*)wxs)[idx] = ((const float4*)wx)[idx];

  // ---- phase 1: conv + silu -> transposed/swizzled LDS ----
  {
    const int ch = tid & (DI - 1);
    const int pb = (tid / DI) * PP;    // 0, or PP for DI=128 upper group
    const long rowb = ((long)bz * DI + ch) * L;
    const float* __restrict__ src = xcpre_t + rowb + l0 + pb;
    float p0 = 0.0f, p1 = 0.0f, p2 = 0.0f;
    if (l0 + pb >= 3) { p0 = src[-3]; p1 = src[-2]; p2 = src[-1]; }
    const float w0 = cw[ch*4+0], w1 = cw[ch*4+1], w2 = cw[ch*4+2], w3 = cw[ch*4+3];
    const float cbc = cb[ch];
    const int g = ch >> 2, c = ch & 3;
    float cur[PP];
    #pragma unroll
    for (int k = 0; k < PP; k += 4) {
      const float4 v = *(const float4*)(src + k);
      cur[k] = v.x; cur[k+1] = v.y; cur[k+2] = v.z; cur[k+3] = v.w;
    }
    float vv[PP];
    {
      float s;
      s = cbc; s = fmaf(p0, w0, s); s = fmaf(p1, w1, s); s = fmaf(p2, w2, s);
      s = fmaf(cur[0], w3, s); vv[0] = silu_f(s);
      s = cbc; s = fmaf(p1, w0, s); s = fmaf(p2, w1, s); s = fmaf(cur[0], w2, s);
      s = fmaf(cur[1], w3, s); vv[1] = silu_f(s);
      s = cbc; s = fmaf(p2, w0, s); s = fmaf(cur[0], w1, s); s = fmaf(cur[1], w2, s);
      s = fmaf(cur[2], w3, s); vv[2] = silu_f(s);
      #pragma unroll
      for (int i = 3; i < PP; ++i) {
        s = cbc;
        s = fmaf(cur[i-3], w0, s);
        s = fmaf(cur[i-2], w1, s);
        s = fmaf(cur[i-1], w2, s);
        s = fmaf(cur[i],   w3, s);
        vv[i] = silu_f(s);
      }
    }
    #pragma unroll
    for (int i2 = 0; i2 < PP; ++i2) {
      const int i = pb + i2;
      xcT[i][(((g + i) & (NC - 1)) << 2) + c] = vv[i2];
    }
  }
  __syncthreads();

  // ---- phase 2: out[j][i] = sum_ch wxs[j][ch] * xcT[i][ch] (LDS-only) ----
  for (int q = tid; q < NP * LT; q += 256) {
    const int j = q >> 4;
    const int i = q & 15;
    const float* __restrict__ wr = &wxs[j][0];
    float a0 = 0.0f, a1 = 0.0f, a2 = 0.0f, a3 = 0.0f;
    #pragma unroll 4
    for (int g = 0; g < NC; ++g) {
      const float4 xv = *(const float4*)&xcT[i][((g + i) & (NC - 1)) << 2];
      const float4 wv = *(const float4*)(wr + (g << 2));
      a0 = fmaf(xv.x, wv.x, a0);
      a1 = fmaf(xv.y, wv.y, a1);
      a2 = fmaf(xv.z, wv.z, a2);
      a3 = fmaf(xv.w, wv.w, a3);
    }
    const float val = (a0 + a1) + (a2 + a3);
    if (j < R) xds_g[((long)bz * R + j) * L + l0 + i] = val;
    else       bc_t[((long)bz * 4 + (j - R)) * L + l0 + i] = val;
  }
}

// ---------------------------------------------------------------------------
// Fused selective scan (unchanged from v8: 512 threads x 8 positions).
// ---------------------------------------------------------------------------
template<int R>
__global__ __launch_bounds__(512, 2) void scan_kernel(
    const float* __restrict__ xcpre_t,
    const float* __restrict__ cw, const float* __restrict__ cb,
    const float* __restrict__ xds_g, const float* __restrict__ wdt,
    const float* __restrict__ bdt,
    const float* __restrict__ z_t, const float* __restrict__ bc_t,
    const float* __restrict__ alog, const float* __restrict__ dd,
    float* __restrict__ y_t, int di, int L)
{
  const int ch = blockIdx.x;
  const int bz = blockIdx.y;
  const int tid = threadIdx.x;
  const int lane = tid & 63;
  const int w = tid >> 6;
  const long rowb = ((long)bz * di + ch) * L;
  const long bcb = (long)bz * 4 * L;
  const int l0 = tid * 8;

  __shared__ float wsP0[8], wsQ0[8], wsP1[8], wsQ1[8];

  const float A0 = -__expf(alog[ch * 2 + 0]);
  const float A1 = -__expf(alog[ch * 2 + 1]);
  const float ddc = dd[ch];

  const float w0 = cw[ch*4+0], w1 = cw[ch*4+1], w2 = cw[ch*4+2], w3 = cw[ch*4+3];
  const float cbc = cb[ch];
  float cur[8];
  load8(cur, xcpre_t + rowb + l0);
  float p0 = 0.0f, p1 = 0.0f, p2 = 0.0f;
  if (tid > 0) {
    const float4 h = *(const float4*)(xcpre_t + rowb + l0 - 4);
    p0 = h.y; p1 = h.z; p2 = h.w;
  }
  float xcv[8];
  {
    float s;
    s = cbc; s = fmaf(p0, w0, s); s = fmaf(p1, w1, s); s = fmaf(p2, w2, s);
    s = fmaf(cur[0], w3, s); xcv[0] = silu_f(s);
    s = cbc; s = fmaf(p1, w0, s); s = fmaf(p2, w1, s); s = fmaf(cur[0], w2, s);
    s = fmaf(cur[1], w3, s); xcv[1] = silu_f(s);
    s = cbc; s = fmaf(p2, w0, s); s = fmaf(cur[0], w1, s); s = fmaf(cur[1], w2, s);
    s = fmaf(cur[2], w3, s); xcv[2] = silu_f(s);
    #pragma unroll
    for (int i = 3; i < 8; ++i) {
      s = cbc;
      s = fmaf(cur[i-3], w0, s);
      s = fmaf(cur[i-2], w1, s);
      s = fmaf(cur[i-1], w2, s);
      s = fmaf(cur[i],   w3, s);
      xcv[i] = silu_f(s);
    }
  }

  float wr[R];
  #pragma unroll
  for (int j = 0; j < R; ++j) wr[j] = wdt[ch * R + j];
  const float bv = bdt[ch];
  float sd[8];
  #pragma unroll
  for (int i = 0; i < 8; ++i) sd[i] = bv;
  const float* __restrict__ xp = xds_g + (long)bz * R * L + l0;
  #pragma unroll 2
  for (int j = 0; j < R; ++j) {
    const float wj = wr[j];
    const float4 x0 = *(const float4*)(xp + (long)j * L + 0);
    const float4 x1 = *(const float4*)(xp + (long)j * L + 4);
    sd[0] = fmaf(x0.x, wj, sd[0]); sd[1] = fmaf(x0.y, wj, sd[1]);
    sd[2] = fmaf(x0.z, wj, sd[2]); sd[3] = fmaf(x0.w, wj, sd[3]);
    sd[4] = fmaf(x1.x, wj, sd[4]); sd[5] = fmaf(x1.y, wj, sd[5]);
    sd[6] = fmaf(x1.z, wj, sd[6]); sd[7] = fmaf(x1.w, wj, sd[7]);
  }

  float a0[8], a1[8], u0[8], u1[8];
  float P0 = 1.0f, Q0 = 0.0f, P1 = 1.0f, Q1 = 0.0f;
  #pragma unroll
  for (int c4 = 0; c4 < 2; ++c4) {
    const float4 t0c = *(const float4*)(bc_t + bcb + l0 + c4 * 4);
    const float4 t1c = *(const float4*)(bc_t + bcb + L + l0 + c4 * 4);
    const float t0a[4] = {t0c.x, t0c.y, t0c.z, t0c.w};
    const float t1a[4] = {t1c.x, t1c.y, t1c.z, t1c.w};
    #pragma unroll
    for (int i2 = 0; i2 < 4; ++i2) {
      const int i = c4 * 4 + i2;
      const float dt = softplus_f(sd[i]);
      const float dx = dt * xcv[i];
      a0[i] = __expf(dt * A0);
      a1[i] = __expf(dt * A1);
      u0[i] = dx * t0a[i2];
      u1[i] = dx * t1a[i2];
      Q0 = fmaf(a0[i], Q0, u0[i]); P0 *= a0[i];
      Q1 = fmaf(a1[i], Q1, u1[i]); P1 *= a1[i];
    }
  }

  #pragma unroll
  for (int off = 1; off < 64; off <<= 1) {
    const float pp0 = __shfl_up(P0, off);
    const float qq0 = __shfl_up(Q0, off);
    const float pp1 = __shfl_up(P1, off);
    const float qq1 = __shfl_up(Q1, off);
    if (lane >= off) {
      Q0 = fmaf(P0, qq0, Q0); P0 *= pp0;
      Q1 = fmaf(P1, qq1, Q1); P1 *= pp1;
    }
  }
  if (lane == 63) { wsP0[w] = P0; wsQ0[w] = Q0; wsP1[w] = P1; wsQ1[w] = Q1; }
  __syncthreads();
  float eQ0 = 0.0f, eQ1 = 0.0f;
  for (int ww = 0; ww < w; ++ww) {
    eQ0 = fmaf(wsP0[ww], eQ0, wsQ0[ww]);
    eQ1 = fmaf(wsP1[ww], eQ1, wsQ1[ww]);
  }
  float pP0 = __shfl_up(P0, 1), pQ0 = __shfl_up(Q0, 1);
  float pP1 = __shfl_up(P1, 1), pQ1 = __shfl_up(Q1, 1);
  if (lane == 0) { pP0 = 1.0f; pQ0 = 0.0f; pP1 = 1.0f; pQ1 = 0.0f; }
  float h0 = fmaf(pP0, eQ0, pQ0);
  float h1 = fmaf(pP1, eQ1, pQ1);

  #pragma unroll
  for (int c4 = 0; c4 < 2; ++c4) {
    const float4 c0c = *(const float4*)(bc_t + bcb + 2 * L + l0 + c4 * 4);
    const float4 c1c = *(const float4*)(bc_t + bcb + 3 * L + l0 + c4 * 4);
    const float4 zvc = *(const float4*)(z_t + rowb + l0 + c4 * 4);
    const float c0a[4] = {c0c.x, c0c.y, c0c.z, c0c.w};
    const float c1a[4] = {c1c.x, c1c.y, c1c.z, c1c.w};
    const float zva[4] = {zvc.x, zvc.y, zvc.z, zvc.w};
    float yv[4];
    #pragma unroll
    for (int i2 = 0; i2 < 4; ++i2) {
      const int i = c4 * 4 + i2;
      h0 = fmaf(a0[i], h0, u0[i]);
      h1 = fmaf(a1[i], h1, u1[i]);
      const float y = fmaf(h0, c0a[i2], fmaf(h1, c1a[i2], ddc * xcv[i]));
      yv[i2] = y * silu_f(zva[i2]);
    }
    *(float4*)(y_t + rowb + l0 + c4 * 4) = make_float4(yv[0], yv[1], yv[2], yv[3]);
  }
}

// ---------------------------------------------------------------------------
extern "C" void kernel_launch(void* const* d_in, const int* in_sizes, int n_in,
                              void* d_out, int out_size, void* d_ws, size_t ws_size,
                              hipStream_t stream)
{
  const float* x       = (const float*)d_in[0];
  const float* lin_w   = (const float*)d_in[1];
  const float* lin_b   = (const float*)d_in[2];
  const float* s1_win  = (const float*)d_in[3];
  const float* s1_bin  = (const float*)d_in[4];
  const float* s1_cw   = (const float*)d_in[5];
  const float* s1_cb   = (const float*)d_in[6];
  const float* s1_wx   = (const float*)d_in[7];
  const float* s1_wdt  = (const float*)d_in[8];
  const float* s1_bdt  = (const float*)d_in[9];
  const float* s1_alog = (const float*)d_in[10];
  const float* s1_dd   = (const float*)d_in[11];
  const float* s1_wout = (const float*)d_in[12];
  const float* s1_lnw  = (const float*)d_in[13];
  const float* s1_lnb  = (const float*)d_in[14];
  const float* s2_win  = (const float*)d_in[15];
  const float* s2_bin  = (const float*)d_in[16];
  const float* s2_cw   = (const float*)d_in[17];
  const float* s2_cb   = (const float*)d_in[18];
  const float* s2_wx   = (const float*)d_in[19];
  const float* s2_wdt  = (const float*)d_in[20];
  const float* s2_bdt  = (const float*)d_in[21];
  const float* s2_alog = (const float*)d_in[22];
  const float* s2_dd   = (const float*)d_in[23];
  const float* s2_wout = (const float*)d_in[24];
  const float* s2_lnw  = (const float*)d_in[25];
  const float* s2_lnb  = (const float*)d_in[26];
  float* out = (float*)d_out;

  const int B = 8, L = 4096, M = 32768;
  const long SLOT = 8L * 256 * 4096;   // 8388608 elems = 32 MB
  const long HALF = SLOT / 2;          // 16 MB
  float* ws = (float*)d_ws;
  float* S0f = ws;             u16* S0u = (u16*)S0f;
  float* S1f = ws + SLOT;      u16* S1u = (u16*)S1f;
  float* S2f = ws + 2 * SLOT;  u16* S2u = (u16*)S2f;
  float* SBf = ws + 3 * SLOT;                        // (B,4,L) = 131072
  float* XDS = ws + 3 * SLOT + 131072;               // (B,16,L) = 524288
  u32*   WP  = (u32*)(ws + 3 * SLOT + 131072 + 524288);  // split weights

  const long AN1 = (long)M * 128;   // elems of a (M,128) activation matrix
  const long AN2 = (long)M * 256;   // elems of a (M,256) activation matrix
  u16* S0uB = (u16*)(S0f + HALF);   // second 16MB of slot 0

  // 1. pack weights (split-plane)
  wprep_kernel<<<WTOT / 256, 256, 0, stream>>>(
      s1_win, s1_wout, lin_w, s2_win, s2_wout, (u16*)WP);
  // 2. x (b,128,L) -> split xT (M,128) @ S0u (16 MB)
  tpose_kernel<<<dim3(128, 4, B), 256, 0, stream>>>(x, S0u, AN1, 128, L);
  // 3. stage1 in-proj: -> xcpre1 @ S1f, z1 @ S1f+HALF
  mgemm_kernel<0><<<dim3(2, 256), 256, 0, stream>>>(
      S0u, AN1, (u16*)(WP + WOFF1), WN1, s1_bin, M, 256, 128,
      S1f, S1f + HALF, nullptr, 0, 128, L);
  // 4. proj1: xcpre1 -> xds @ XDS, B/C @ SBf
  proj_kernel<128, 8><<<dim3(256, B), 256, 0, stream>>>(
      S1f, s1_cw, s1_cb, s1_wx, XDS, SBf, L);
  // 5. fused scan1 (conv+dt recompute) -> y1 @ S2f
  scan_kernel<8><<<dim3(128, B), 512, 0, stream>>>(
      S1f, s1_cw, s1_cb, XDS, s1_wdt, s1_bdt, S1f + HALF, SBf,
      s1_alog, s1_dd, S2f, 128, L);
  // 6. y1 (S2f) -> split y1T @ S0uB
  tpose_kernel<<<dim3(128, 4, B), 256, 0, stream>>>(S2f, S0uB, AN1, 128, L);
  // 7. out-proj1 + LN -> act_mid split @ S1u
  lgemm_kernel<128, 2><<<dim3(512), 256, 0, stream>>>(
      S0uB, AN1, (u16*)(WP + WOFFO1), WNO1, s1_lnw, s1_lnb,
      M, 128, S1u, AN1, nullptr, L);
  // 8. mid linear + silu -> act_lin split @ S2u (32 MB; y1 dead)
  mgemm_kernel<1><<<dim3(2, 256), 256, 0, stream>>>(
      S1u, AN1, (u16*)(WP + WOFFL), WNL, lin_b, M, 256, 128,
      nullptr, nullptr, S2u, AN2, 0, L);
  // 9. stage2 in-proj: -> xcpre2 @ S0f, z2 @ S1f
  mgemm_kernel<0><<<dim3(4, 256), 256, 0, stream>>>(
      S2u, AN2, (u16*)(WP + WOFF2), WN2, s2_bin, M, 512, 256,
      S0f, S1f, nullptr, 0, 256, L);
  // 10. proj2: xcpre2 -> xds @ XDS, B/C @ SBf
  proj_kernel<256, 16><<<dim3(256, B), 256, 0, stream>>>(
      S0f, s2_cw, s2_cb, s2_wx, XDS, SBf, L);
  // 11. fused scan2 -> y2 @ S2f (act_lin dead after step 9)
  scan_kernel<16><<<dim3(256, B), 512, 0, stream>>>(
      S0f, s2_cw, s2_cb, XDS, s2_wdt, s2_bdt, S1f, SBf,
      s2_alog, s2_dd, S2f, 256, L);
  // 12. y2 -> split y2T @ S1u
  tpose_kernel<<<dim3(128, 8, B), 256, 0, stream>>>(S2f, S1u, AN2, 256, L);
  // 13. out-proj2 + LN -> d_out fp32 (b,256,64,64)
  lgemm_kernel<256, 3><<<dim3(512), 256, 0, stream>>>(
      S1u, AN2, (u16*)(WP + WOFFO2), WNO2, s2_lnw, s2_lnb,
      M, 256, nullptr, 0, out, L);
}

// Round 13
// 329.523 us; speedup vs baseline: 1.0439x; 1.0439x over previous
//
#include <hip/hip_runtime.h>
#include <math.h>

#define DEVI __device__ __forceinline__

typedef unsigned int u32;
typedef unsigned short u16;
typedef __attribute__((ext_vector_type(8))) __bf16 bf16x8;
typedef __attribute__((ext_vector_type(8))) u16 u16x8;
typedef __attribute__((ext_vector_type(4))) float f32x4;

DEVI float rcp_f(float x) { return __builtin_amdgcn_rcpf(x); }
DEVI float silu_f(float x) { return x * rcp_f(1.0f + __expf(-x)); }
// fast softplus: max(x,0) + log(1+exp(-|x|)); abs err < 1e-7.
DEVI float softplus_f(float x) {
  return fmaxf(x, 0.0f) + __logf(1.0f + __expf(-fabsf(x)));
}

DEVI u32 bf16_rne(float f) {
  u32 u = __float_as_uint(f);
  return (u + 0x7fffu + ((u >> 16) & 1u)) >> 16;
}
// split-plane store: H plane at [0,PN), L plane at [PN,2PN).
DEVI void split_store(u16* __restrict__ p, long idx, long PN, float v) {
  const u32 h = bf16_rne(v);
  const float hf = __uint_as_float(h << 16);
  p[idx] = (u16)h;
  p[PN + idx] = (u16)bf16_rne(v - hf);
}

DEVI void load8(float* r, const float* __restrict__ p) {
  const float4* q = (const float4*)p;
  float4 a = q[0], b = q[1];
  r[0]=a.x; r[1]=a.y; r[2]=a.z; r[3]=a.w;
  r[4]=b.x; r[5]=b.y; r[6]=b.z; r[7]=b.w;
}

// ---------------------------------------------------------------------------
// Weight prep: fp32 -> split-plane bf16 hi/lo. Region: [H (N u16)][L (N u16)].
// ---------------------------------------------------------------------------
constexpr int WN1 = 32768, WNO1 = 16384, WNL = 32768, WN2 = 131072, WNO2 = 65536;
constexpr int WOFF1 = 0, WOFFO1 = 32768, WOFFL = 49152, WOFF2 = 81920, WOFFO2 = 212992;
constexpr int WTOT = 278528;

__global__ __launch_bounds__(256) void wprep_kernel(
    const float* __restrict__ w1, const float* __restrict__ wo1,
    const float* __restrict__ wl, const float* __restrict__ w2,
    const float* __restrict__ wo2, u16* __restrict__ dst)
{
  int i = blockIdx.x * 256 + threadIdx.x;
  float v;
  long rb, rn;
  if (i < WOFFO1)       { v = w1[i];            rb = WOFF1;  rn = WN1; }
  else if (i < WOFFL)   { v = wo1[i - WOFFO1];  rb = WOFFO1; rn = WNO1; }
  else if (i < WOFF2)   { v = wl[i - WOFFL];    rb = WOFFL;  rn = WNL; }
  else if (i < WOFFO2)  { v = w2[i - WOFF2];    rb = WOFF2;  rn = WN2; }
  else                  { v = wo2[i - WOFFO2];  rb = WOFFO2; rn = WNO2; }
  split_store(dst + 2 * rb, i - rb, rn, v);
}

// ---------------------------------------------------------------------------
// MFMA GEMM (bf16x3 split): C[m,n] = sum_k A[m,k]*W[n,k] (+bias)
// v14: AF=1 -> A read directly from fp32 channel-major (b,K,L) with in-kernel
// hi/lo bf16 split (bit-identical to the old tpose path) — deletes the
// standalone transpose pass. AF=0 -> split-plane A (rows m, cols k).
// Register-prefetch dbuf + XCD swizzle + natural (no-XOR) LDS layout kept.
// ---------------------------------------------------------------------------
template<int EPI, int AF>
__global__ __launch_bounds__(256) void mgemm_kernel(
    const u16* __restrict__ Ap, long AN, const float* __restrict__ Af,
    const u16* __restrict__ Wp, long WN,
    const float* __restrict__ bias, int M, int N, int K,
    float* __restrict__ out0, float* __restrict__ out1,
    u16* __restrict__ outp, long PN, int di, int L)
{
  __shared__ u16 Ah[128][40], Al[128][40], Bh[128][40], Bl[128][40];
  const int tid = threadIdx.x;
  const int wid = tid >> 6, lane = tid & 63;
  const int lm = lane & 15, lq = lane >> 4;

  // XCD-chunked swizzle
  int bx = blockIdx.x, by = blockIdx.y;
  {
    const int nwg = gridDim.x * gridDim.y;
    if ((nwg & 7) == 0) {
      int flat = by * gridDim.x + bx;
      const int q = nwg >> 3;
      flat = (flat & 7) * q + (flat >> 3);
      bx = flat % gridDim.x;
      by = flat / gridDim.x;
    }
  }
  const int m0 = by * 128, n0 = bx * 128;
  const int wr = (wid >> 1) * 64, wn = (wid & 1) * 64;
  const int sr = tid >> 1;
  const int sc = (tid & 1) * 2;
  const int o0 = (sc + 0) * 8;
  const int o1 = (sc + 1) * 8;

  f32x4 acc[4][4];
  #pragma unroll
  for (int i = 0; i < 4; ++i)
    #pragma unroll
    for (int j = 0; j < 4; ++j)
      #pragma unroll
      for (int r = 0; r < 4; ++r) acc[i][j][r] = 0.0f;

  const u16* gaH = Ap + (long)(m0 + sr) * K + sc * 8;
  const u16* gaL = gaH + AN;
  const float* ax = nullptr;
  if constexpr (AF) {
    const int ab = m0 >> 12;               // 128-row tiles never cross batch
    const int al = (m0 & 4095) + sr;
    ax = Af + (long)ab * K * L + al;       // + ch*L per element
  }
  const u16* gbH = Wp + (long)(n0 + sr) * K + sc * 8;
  const u16* gbL = gbH + WN;
  const int co = lq * 8;
  const int nt = K >> 5;

  // prefetch registers
  float av[16];
  uint4 ah0, ah1, al0, al1;
  uint4 bh0, bh1, bl0, bl1;

  // preload tile 0
  if constexpr (AF) {
    #pragma unroll
    for (int kk = 0; kk < 16; ++kk) av[kk] = ax[(long)(sc * 8 + kk) * L];
  } else {
    ah0 = *(const uint4*)(gaH);
    ah1 = *(const uint4*)(gaH + 8);
    al0 = *(const uint4*)(gaL);
    al1 = *(const uint4*)(gaL + 8);
  }
  bh0 = *(const uint4*)(gbH);
  bh1 = *(const uint4*)(gbH + 8);
  bl0 = *(const uint4*)(gbL);
  bl1 = *(const uint4*)(gbL + 8);

  for (int kt = 0; kt < nt; ++kt) {
    if constexpr (AF) {
      u16x8 h0v, h1v, l0v, l1v;
      #pragma unroll
      for (int kk = 0; kk < 8; ++kk) {
        const u32 hh = bf16_rne(av[kk]);
        h0v[kk] = (u16)hh;
        l0v[kk] = (u16)bf16_rne(av[kk] - __uint_as_float(hh << 16));
        const u32 h2 = bf16_rne(av[kk + 8]);
        h1v[kk] = (u16)h2;
        l1v[kk] = (u16)bf16_rne(av[kk + 8] - __uint_as_float(h2 << 16));
      }
      *(u16x8*)&Ah[sr][o0] = h0v; *(u16x8*)&Ah[sr][o1] = h1v;
      *(u16x8*)&Al[sr][o0] = l0v; *(u16x8*)&Al[sr][o1] = l1v;
    } else {
      *(uint4*)&Ah[sr][o0] = ah0; *(uint4*)&Ah[sr][o1] = ah1;
      *(uint4*)&Al[sr][o0] = al0; *(uint4*)&Al[sr][o1] = al1;
    }
    *(uint4*)&Bh[sr][o0] = bh0; *(uint4*)&Bh[sr][o1] = bh1;
    *(uint4*)&Bl[sr][o0] = bl0; *(uint4*)&Bl[sr][o1] = bl1;
    __syncthreads();

    if (kt + 1 < nt) {
      const int k0 = (kt + 1) << 5;
      if constexpr (AF) {
        #pragma unroll
        for (int kk = 0; kk < 16; ++kk)
          av[kk] = ax[(long)(k0 + sc * 8 + kk) * L];
      } else {
        ah0 = *(const uint4*)(gaH + k0);
        ah1 = *(const uint4*)(gaH + k0 + 8);
        al0 = *(const uint4*)(gaL + k0);
        al1 = *(const uint4*)(gaL + k0 + 8);
      }
      bh0 = *(const uint4*)(gbH + k0);
      bh1 = *(const uint4*)(gbH + k0 + 8);
      bl0 = *(const uint4*)(gbL + k0);
      bl1 = *(const uint4*)(gbL + k0 + 8);
    }

    bf16x8 fah[4], fal[4];
    #pragma unroll
    for (int i = 0; i < 4; ++i) {
      fah[i] = *(const bf16x8*)&Ah[wr + 16 * i + lm][co];
      fal[i] = *(const bf16x8*)&Al[wr + 16 * i + lm][co];
    }
    #pragma unroll
    for (int j = 0; j < 4; ++j) {
      bf16x8 fbh = *(const bf16x8*)&Bh[wn + 16 * j + lm][co];
      bf16x8 fbl = *(const bf16x8*)&Bl[wn + 16 * j + lm][co];
      #pragma unroll
      for (int i = 0; i < 4; ++i) {
        acc[i][j] = __builtin_amdgcn_mfma_f32_16x16x32_bf16(fah[i], fbh, acc[i][j], 0, 0, 0);
        acc[i][j] = __builtin_amdgcn_mfma_f32_16x16x32_bf16(fah[i], fbl, acc[i][j], 0, 0, 0);
        acc[i][j] = __builtin_amdgcn_mfma_f32_16x16x32_bf16(fal[i], fbh, acc[i][j], 0, 0, 0);
      }
    }
    __syncthreads();
  }

  if constexpr (EPI == 0) {
    const int b = m0 >> 12;
    const int lb = (m0 & 4095) + wr;
    #pragma unroll
    for (int j = 0; j < 4; ++j) {
      const int n = n0 + wn + 16 * j + lm;
      const float bv = bias[n];
      float* base = (n < di) ? out0 + ((long)b * di + n) * L
                             : out1 + ((long)b * di + (n - di)) * L;
      #pragma unroll
      for (int i = 0; i < 4; ++i) {
        const int l = lb + 16 * i + lq * 4;
        *(float4*)(base + l) = make_float4(acc[i][j][0] + bv, acc[i][j][1] + bv,
                                           acc[i][j][2] + bv, acc[i][j][3] + bv);
      }
    }
  } else {
    #pragma unroll
    for (int j = 0; j < 4; ++j) {
      const int n = n0 + wn + 16 * j + lm;
      const float bv = bias[n];
      #pragma unroll
      for (int i = 0; i < 4; ++i) {
        const long mg = m0 + wr + 16 * i + lq * 4;
        #pragma unroll
        for (int r = 0; r < 4; ++r)
          split_store(outp, (mg + r) * N + n, PN, silu_f(acc[i][j][r] + bv));
      }
    }
  }
}

// ---------------------------------------------------------------------------
// MFMA GEMM + fused LayerNorm over full width BN.
// v14: A read directly from fp32 channel-major (b,K,L) (scan output y),
// hi/lo split done in-kernel during staging — deletes the y->yT transpose.
// ---------------------------------------------------------------------------
template<int BN, int EPI>
__global__ __launch_bounds__(256) void lgemm_kernel(
    const float* __restrict__ Af, const u16* __restrict__ Wp, long WN,
    const float* __restrict__ lnw, const float* __restrict__ lnb,
    int M, int K, u16* __restrict__ outp, long PN, float* __restrict__ outf, int L)
{
  constexpr int NT = BN / 64;
  __shared__ u16 Ah[64][40], Al[64][40], Bh[BN][40], Bl[BN][40];
  __shared__ float red[4][64];
  __shared__ float muS[64], rsS[64];

  const int tid = threadIdx.x;
  const int wid = tid >> 6, lane = tid & 63;
  const int lm = lane & 15, lq = lane >> 4;
  const int m0 = blockIdx.x * 64;
  const int wn = wid * (BN / 4);
  const int sa_r = tid >> 2, sa_c = tid & 3;
  const int sa_o = sa_c * 8;
  const int co = lq * 8;

  f32x4 acc[4][NT];
  #pragma unroll
  for (int i = 0; i < 4; ++i)
    #pragma unroll
    for (int j = 0; j < NT; ++j)
      #pragma unroll
      for (int r = 0; r < 4; ++r) acc[i][j][r] = 0.0f;

  const int ab = m0 >> 12;             // 64-row tiles never cross batch
  const int al = (m0 & 4095) + sa_r;
  const float* ax = Af + (long)ab * K * L + al;

  for (int k0 = 0; k0 < K; k0 += 32) {
    {
      float av[8];
      #pragma unroll
      for (int kk = 0; kk < 8; ++kk)
        av[kk] = ax[(long)(k0 + sa_c * 8 + kk) * L];
      u16x8 hv, lv;
      #pragma unroll
      for (int kk = 0; kk < 8; ++kk) {
        const u32 hh = bf16_rne(av[kk]);
        hv[kk] = (u16)hh;
        lv[kk] = (u16)bf16_rne(av[kk] - __uint_as_float(hh << 16));
      }
      *(u16x8*)&Ah[sa_r][sa_o] = hv;
      *(u16x8*)&Al[sa_r][sa_o] = lv;
    }
    #pragma unroll
    for (int it = 0; it < NT; ++it) {
      const int idx = tid + it * 256;
      const int n = idx >> 2, c = idx & 3;
      const u16* gwH = Wp + (long)n * K + k0 + c * 8;
      uint4 bh = *(const uint4*)gwH;
      uint4 bl = *(const uint4*)(gwH + WN);
      const int o = c * 8;
      *(uint4*)&Bh[n][o] = bh;
      *(uint4*)&Bl[n][o] = bl;
    }
    __syncthreads();

    bf16x8 fah[4], fal[4];
    #pragma unroll
    for (int i = 0; i < 4; ++i) {
      fah[i] = *(const bf16x8*)&Ah[16 * i + lm][co];
      fal[i] = *(const bf16x8*)&Al[16 * i + lm][co];
    }
    #pragma unroll
    for (int j = 0; j < NT; ++j) {
      bf16x8 fbh = *(const bf16x8*)&Bh[wn + 16 * j + lm][co];
      bf16x8 fbl = *(const bf16x8*)&Bl[wn + 16 * j + lm][co];
      #pragma unroll
      for (int i = 0; i < 4; ++i) {
        acc[i][j] = __builtin_amdgcn_mfma_f32_16x16x32_bf16(fah[i], fbh, acc[i][j], 0, 0, 0);
        acc[i][j] = __builtin_amdgcn_mfma_f32_16x16x32_bf16(fah[i], fbl, acc[i][j], 0, 0, 0);
        acc[i][j] = __builtin_amdgcn_mfma_f32_16x16x32_bf16(fal[i], fbh, acc[i][j], 0, 0, 0);
      }
    }
    __syncthreads();
  }

  // ---- fused LayerNorm over BN ----
  float part[4][4];
  #pragma unroll
  for (int i = 0; i < 4; ++i)
    #pragma unroll
    for (int r = 0; r < 4; ++r) {
      float s = 0.0f;
      #pragma unroll
      for (int j = 0; j < NT; ++j) s += acc[i][j][r];
      part[i][r] = s;
    }
  #pragma unroll
  for (int off = 1; off < 16; off <<= 1)
    #pragma unroll
    for (int i = 0; i < 4; ++i)
      #pragma unroll
      for (int r = 0; r < 4; ++r) part[i][r] += __shfl_xor(part[i][r], off);
  if (lm == 0) {
    #pragma unroll
    for (int i = 0; i < 4; ++i)
      #pragma unroll
      for (int r = 0; r < 4; ++r) red[wid][16 * i + 4 * lq + r] = part[i][r];
  }
  __syncthreads();
  if (tid < 64)
    muS[tid] = (red[0][tid] + red[1][tid] + red[2][tid] + red[3][tid]) * (1.0f / BN);
  __syncthreads();
  float mu_l[4][4];
  #pragma unroll
  for (int i = 0; i < 4; ++i)
    #pragma unroll
    for (int r = 0; r < 4; ++r) mu_l[i][r] = muS[16 * i + 4 * lq + r];
  #pragma unroll
  for (int i = 0; i < 4; ++i)
    #pragma unroll
    for (int r = 0; r < 4; ++r) {
      float s = 0.0f;
      #pragma unroll
      for (int j = 0; j < NT; ++j) {
        float d = acc[i][j][r] - mu_l[i][r];
        s = fmaf(d, d, s);
      }
      part[i][r] = s;
    }
  #pragma unroll
  for (int off = 1; off < 16; off <<= 1)
    #pragma unroll
    for (int i = 0; i < 4; ++i)
      #pragma unroll
      for (int r = 0; r < 4; ++r) part[i][r] += __shfl_xor(part[i][r], off);
  if (lm == 0) {
    #pragma unroll
    for (int i = 0; i < 4; ++i)
      #pragma unroll
      for (int r = 0; r < 4; ++r) red[wid][16 * i + 4 * lq + r] = part[i][r];
  }
  __syncthreads();
  if (tid < 64)
    rsS[tid] = rsqrtf((red[0][tid] + red[1][tid] + red[2][tid] + red[3][tid]) * (1.0f / BN)
                      + 1e-5f);
  __syncthreads();
  float rs_l[4][4];
  #pragma unroll
  for (int i = 0; i < 4; ++i)
    #pragma unroll
    for (int r = 0; r < 4; ++r) rs_l[i][r] = rsS[16 * i + 4 * lq + r];

  if constexpr (EPI == 2) {
    #pragma unroll
    for (int j = 0; j < NT; ++j) {
      const int n = wn + 16 * j + lm;
      const float g = lnw[n], bb = lnb[n];
      #pragma unroll
      for (int i = 0; i < 4; ++i) {
        #pragma unroll
        for (int r = 0; r < 4; ++r) {
          const long mg = m0 + 16 * i + 4 * lq + r;
          split_store(outp, mg * BN + n, PN,
                      (acc[i][j][r] - mu_l[i][r]) * rs_l[i][r] * g + bb);
        }
      }
    }
  } else {
    const int b = m0 >> 12;
    const int lb = m0 & 4095;
    #pragma unroll
    for (int j = 0; j < NT; ++j) {
      const int n = wn + 16 * j + lm;
      const float g = lnw[n], bb = lnb[n];
      #pragma unroll
      for (int i = 0; i < 4; ++i) {
        const int l = lb + 16 * i + 4 * lq;
        float4 v;
        v.x = (acc[i][j][0] - mu_l[i][0]) * rs_l[i][0] * g + bb;
        v.y = (acc[i][j][1] - mu_l[i][1]) * rs_l[i][1] * g + bb;
        v.z = (acc[i][j][2] - mu_l[i][2]) * rs_l[i][2] * g + bb;
        v.w = (acc[i][j][3] - mu_l[i][3]) * rs_l[i][3] * g + bb;
        *(float4*)(outf + ((long)b * BN + n) * L + l) = v;
      }
    }
  }
}

// ---------------------------------------------------------------------------
// Projection: conv(4)+silu (into transposed/swizzled LDS) -> xds/bc.
// ---------------------------------------------------------------------------
template<int DI, int R>
__global__ __launch_bounds__(256) void proj_kernel(
    const float* __restrict__ xcpre_t,
    const float* __restrict__ cw, const float* __restrict__ cb,
    const float* __restrict__ wx,
    float* __restrict__ xds_g, float* __restrict__ bc_t, int L)
{
  constexpr int LT = 16;
  constexpr int NP = R + 4;
  constexpr int NC = DI / 4;
  constexpr int NG = 256 / DI;
  constexpr int PP = LT / NG;
  __shared__ float xcT[LT][DI];
  __shared__ float wxs[NP][DI];

  const int tid = threadIdx.x;
  const int l0 = blockIdx.x * LT;
  const int bz = blockIdx.y;

  for (int idx = tid; idx < NP * NC; idx += 256)
    ((float4*)wxs)[idx] = ((const float4*)wx)[idx];

  {
    const int ch = tid & (DI - 1);
    const int pb = (tid / DI) * PP;
    const long rowb = ((long)bz * DI + ch) * L;
    const float* __restrict__ src = xcpre_t + rowb + l0 + pb;
    float p0 = 0.0f, p1 = 0.0f, p2 = 0.0f;
    if (l0 + pb >= 3) { p0 = src[-3]; p1 = src[-2]; p2 = src[-1]; }
    const float w0 = cw[ch*4+0], w1 = cw[ch*4+1], w2 = cw[ch*4+2], w3 = cw[ch*4+3];
    const float cbc = cb[ch];
    const int g = ch >> 2, c = ch & 3;
    float cur[PP];
    #pragma unroll
    for (int k = 0; k < PP; k += 4) {
      const float4 v = *(const float4*)(src + k);
      cur[k] = v.x; cur[k+1] = v.y; cur[k+2] = v.z; cur[k+3] = v.w;
    }
    float vv[PP];
    {
      float s;
      s = cbc; s = fmaf(p0, w0, s); s = fmaf(p1, w1, s); s = fmaf(p2, w2, s);
      s = fmaf(cur[0], w3, s); vv[0] = silu_f(s);
      s = cbc; s = fmaf(p1, w0, s); s = fmaf(p2, w1, s); s = fmaf(cur[0], w2, s);
      s = fmaf(cur[1], w3, s); vv[1] = silu_f(s);
      s = cbc; s = fmaf(p2, w0, s); s = fmaf(cur[0], w1, s); s = fmaf(cur[1], w2, s);
      s = fmaf(cur[2], w3, s); vv[2] = silu_f(s);
      #pragma unroll
      for (int i = 3; i < PP; ++i) {
        s = cbc;
        s = fmaf(cur[i-3], w0, s);
        s = fmaf(cur[i-2], w1, s);
        s = fmaf(cur[i-1], w2, s);
        s = fmaf(cur[i],   w3, s);
        vv[i] = silu_f(s);
      }
    }
    #pragma unroll
    for (int i2 = 0; i2 < PP; ++i2) {
      const int i = pb + i2;
      xcT[i][(((g + i) & (NC - 1)) << 2) + c] = vv[i2];
    }
  }
  __syncthreads();

  for (int q = tid; q < NP * LT; q += 256) {
    const int j = q >> 4;
    const int i = q & 15;
    const float* __restrict__ wr = &wxs[j][0];
    float a0 = 0.0f, a1 = 0.0f, a2 = 0.0f, a3 = 0.0f;
    #pragma unroll 4
    for (int g = 0; g < NC; ++g) {
      const float4 xv = *(const float4*)&xcT[i][((g + i) & (NC - 1)) << 2];
      const float4 wv = *(const float4*)(wr + (g << 2));
      a0 = fmaf(xv.x, wv.x, a0);
      a1 = fmaf(xv.y, wv.y, a1);
      a2 = fmaf(xv.z, wv.z, a2);
      a3 = fmaf(xv.w, wv.w, a3);
    }
    const float val = (a0 + a1) + (a2 + a3);
    if (j < R) xds_g[((long)bz * R + j) * L + l0 + i] = val;
    else       bc_t[((long)bz * 4 + (j - R)) * L + l0 + i] = val;
  }
}

// ---------------------------------------------------------------------------
// Fused selective scan (512 threads x 8 positions).
// ---------------------------------------------------------------------------
template<int R>
__global__ __launch_bounds__(512, 2) void scan_kernel(
    const float* __restrict__ xcpre_t,
    const float* __restrict__ cw, const float* __restrict__ cb,
    const float* __restrict__ xds_g, const float* __restrict__ wdt,
    const float* __restrict__ bdt,
    const float* __restrict__ z_t, const float* __restrict__ bc_t,
    const float* __restrict__ alog, const float* __restrict__ dd,
    float* __restrict__ y_t, int di, int L)
{
  const int ch = blockIdx.x;
  const int bz = blockIdx.y;
  const int tid = threadIdx.x;
  const int lane = tid & 63;
  const int w = tid >> 6;
  const long rowb = ((long)bz * di + ch) * L;
  const long bcb = (long)bz * 4 * L;
  const int l0 = tid * 8;

  __shared__ float wsP0[8], wsQ0[8], wsP1[8], wsQ1[8];

  const float A0 = -__expf(alog[ch * 2 + 0]);
  const float A1 = -__expf(alog[ch * 2 + 1]);
  const float ddc = dd[ch];

  const float w0 = cw[ch*4+0], w1 = cw[ch*4+1], w2 = cw[ch*4+2], w3 = cw[ch*4+3];
  const float cbc = cb[ch];
  float cur[8];
  load8(cur, xcpre_t + rowb + l0);
  float p0 = 0.0f, p1 = 0.0f, p2 = 0.0f;
  if (tid > 0) {
    const float4 h = *(const float4*)(xcpre_t + rowb + l0 - 4);
    p0 = h.y; p1 = h.z; p2 = h.w;
  }
  float xcv[8];
  {
    float s;
    s = cbc; s = fmaf(p0, w0, s); s = fmaf(p1, w1, s); s = fmaf(p2, w2, s);
    s = fmaf(cur[0], w3, s); xcv[0] = silu_f(s);
    s = cbc; s = fmaf(p1, w0, s); s = fmaf(p2, w1, s); s = fmaf(cur[0], w2, s);
    s = fmaf(cur[1], w3, s); xcv[1] = silu_f(s);
    s = cbc; s = fmaf(p2, w0, s); s = fmaf(cur[0], w1, s); s = fmaf(cur[1], w2, s);
    s = fmaf(cur[2], w3, s); xcv[2] = silu_f(s);
    #pragma unroll
    for (int i = 3; i < 8; ++i) {
      s = cbc;
      s = fmaf(cur[i-3], w0, s);
      s = fmaf(cur[i-2], w1, s);
      s = fmaf(cur[i-1], w2, s);
      s = fmaf(cur[i],   w3, s);
      xcv[i] = silu_f(s);
    }
  }

  float wr[R];
  #pragma unroll
  for (int j = 0; j < R; ++j) wr[j] = wdt[ch * R + j];
  const float bv = bdt[ch];
  float sd[8];
  #pragma unroll
  for (int i = 0; i < 8; ++i) sd[i] = bv;
  const float* __restrict__ xp = xds_g + (long)bz * R * L + l0;
  #pragma unroll 2
  for (int j = 0; j < R; ++j) {
    const float wj = wr[j];
    const float4 x0 = *(const float4*)(xp + (long)j * L + 0);
    const float4 x1 = *(const float4*)(xp + (long)j * L + 4);
    sd[0] = fmaf(x0.x, wj, sd[0]); sd[1] = fmaf(x0.y, wj, sd[1]);
    sd[2] = fmaf(x0.z, wj, sd[2]); sd[3] = fmaf(x0.w, wj, sd[3]);
    sd[4] = fmaf(x1.x, wj, sd[4]); sd[5] = fmaf(x1.y, wj, sd[5]);
    sd[6] = fmaf(x1.z, wj, sd[6]); sd[7] = fmaf(x1.w, wj, sd[7]);
  }

  float a0[8], a1[8], u0[8], u1[8];
  float P0 = 1.0f, Q0 = 0.0f, P1 = 1.0f, Q1 = 0.0f;
  #pragma unroll
  for (int c4 = 0; c4 < 2; ++c4) {
    const float4 t0c = *(const float4*)(bc_t + bcb + l0 + c4 * 4);
    const float4 t1c = *(const float4*)(bc_t + bcb + L + l0 + c4 * 4);
    const float t0a[4] = {t0c.x, t0c.y, t0c.z, t0c.w};
    const float t1a[4] = {t1c.x, t1c.y, t1c.z, t1c.w};
    #pragma unroll
    for (int i2 = 0; i2 < 4; ++i2) {
      const int i = c4 * 4 + i2;
      const float dt = softplus_f(sd[i]);
      const float dx = dt * xcv[i];
      a0[i] = __expf(dt * A0);
      a1[i] = __expf(dt * A1);
      u0[i] = dx * t0a[i2];
      u1[i] = dx * t1a[i2];
      Q0 = fmaf(a0[i], Q0, u0[i]); P0 *= a0[i];
      Q1 = fmaf(a1[i], Q1, u1[i]); P1 *= a1[i];
    }
  }

  #pragma unroll
  for (int off = 1; off < 64; off <<= 1) {
    const float pp0 = __shfl_up(P0, off);
    const float qq0 = __shfl_up(Q0, off);
    const float pp1 = __shfl_up(P1, off);
    const float qq1 = __shfl_up(Q1, off);
    if (lane >= off) {
      Q0 = fmaf(P0, qq0, Q0); P0 *= pp0;
      Q1 = fmaf(P1, qq1, Q1); P1 *= pp1;
    }
  }
  if (lane == 63) { wsP0[w] = P0; wsQ0[w] = Q0; wsP1[w] = P1; wsQ1[w] = Q1; }
  __syncthreads();
  float eQ0 = 0.0f, eQ1 = 0.0f;
  for (int ww = 0; ww < w; ++ww) {
    eQ0 = fmaf(wsP0[ww], eQ0, wsQ0[ww]);
    eQ1 = fmaf(wsP1[ww], eQ1, wsQ1[ww]);
  }
  float pP0 = __shfl_up(P0, 1), pQ0 = __shfl_up(Q0, 1);
  float pP1 = __shfl_up(P1, 1), pQ1 = __shfl_up(Q1, 1);
  if (lane == 0) { pP0 = 1.0f; pQ0 = 0.0f; pP1 = 1.0f; pQ1 = 0.0f; }
  float h0 = fmaf(pP0, eQ0, pQ0);
  float h1 = fmaf(pP1, eQ1, pQ1);

  #pragma unroll
  for (int c4 = 0; c4 < 2; ++c4) {
    const float4 c0c = *(const float4*)(bc_t + bcb + 2 * L + l0 + c4 * 4);
    const float4 c1c = *(const float4*)(bc_t + bcb + 3 * L + l0 + c4 * 4);
    const float4 zvc = *(const float4*)(z_t + rowb + l0 + c4 * 4);
    const float c0a[4] = {c0c.x, c0c.y, c0c.z, c0c.w};
    const float c1a[4] = {c1c.x, c1c.y, c1c.z, c1c.w};
    const float zva[4] = {zvc.x, zvc.y, zvc.z, zvc.w};
    float yv[4];
    #pragma unroll
    for (int i2 = 0; i2 < 4; ++i2) {
      const int i = c4 * 4 + i2;
      h0 = fmaf(a0[i], h0, u0[i]);
      h1 = fmaf(a1[i], h1, u1[i]);
      const float y = fmaf(h0, c0a[i2], fmaf(h1, c1a[i2], ddc * xcv[i]));
      yv[i2] = y * silu_f(zva[i2]);
    }
    *(float4*)(y_t + rowb + l0 + c4 * 4) = make_float4(yv[0], yv[1], yv[2], yv[3]);
  }
}

// ---------------------------------------------------------------------------
extern "C" void kernel_launch(void* const* d_in, const int* in_sizes, int n_in,
                              void* d_out, int out_size, void* d_ws, size_t ws_size,
                              hipStream_t stream)
{
  const float* x       = (const float*)d_in[0];
  const float* lin_w   = (const float*)d_in[1];
  const float* lin_b   = (const float*)d_in[2];
  const float* s1_win  = (const float*)d_in[3];
  const float* s1_bin  = (const float*)d_in[4];
  const float* s1_cw   = (const float*)d_in[5];
  const float* s1_cb   = (const float*)d_in[6];
  const float* s1_wx   = (const float*)d_in[7];
  const float* s1_wdt  = (const float*)d_in[8];
  const float* s1_bdt  = (const float*)d_in[9];
  const float* s1_alog = (const float*)d_in[10];
  const float* s1_dd   = (const float*)d_in[11];
  const float* s1_wout = (const float*)d_in[12];
  const float* s1_lnw  = (const float*)d_in[13];
  const float* s1_lnb  = (const float*)d_in[14];
  const float* s2_win  = (const float*)d_in[15];
  const float* s2_bin  = (const float*)d_in[16];
  const float* s2_cw   = (const float*)d_in[17];
  const float* s2_cb   = (const float*)d_in[18];
  const float* s2_wx   = (const float*)d_in[19];
  const float* s2_wdt  = (const float*)d_in[20];
  const float* s2_bdt  = (const float*)d_in[21];
  const float* s2_alog = (const float*)d_in[22];
  const float* s2_dd   = (const float*)d_in[23];
  const float* s2_wout = (const float*)d_in[24];
  const float* s2_lnw  = (const float*)d_in[25];
  const float* s2_lnb  = (const float*)d_in[26];
  float* out = (float*)d_out;

  const int B = 8, L = 4096, M = 32768;
  const long SLOT = 8L * 256 * 4096;   // 8388608 elems = 32 MB
  const long HALF = SLOT / 2;          // 16 MB
  float* ws = (float*)d_ws;
  float* S0f = ws;
  float* S1f = ws + SLOT;      u16* S1u = (u16*)S1f;
  float* S2f = ws + 2 * SLOT;  u16* S2u = (u16*)S2f;
  float* SBf = ws + 3 * SLOT;                        // (B,4,L) = 131072
  float* XDS = ws + 3 * SLOT + 131072;               // (B,16,L) = 524288
  u32*   WP  = (u32*)(ws + 3 * SLOT + 131072 + 524288);  // split weights

  const long AN1 = (long)M * 128;   // elems of a (M,128) activation matrix
  const long AN2 = (long)M * 256;   // elems of a (M,256) activation matrix

  // 1. pack weights (split-plane)
  wprep_kernel<<<WTOT / 256, 256, 0, stream>>>(
      s1_win, s1_wout, lin_w, s2_win, s2_wout, (u16*)WP);
  // 2. stage1 in-proj: A = x fp32 channel-major (AF=1) -> xcpre1 @ S1f,
  //    z1 @ S1f+HALF
  mgemm_kernel<0, 1><<<dim3(2, 256), 256, 0, stream>>>(
      nullptr, 0, x, (u16*)(WP + WOFF1), WN1, s1_bin, M, 256, 128,
      S1f, S1f + HALF, nullptr, 0, 128, L);
  // 3. proj1: xcpre1 -> xds @ XDS, B/C @ SBf
  proj_kernel<128, 8><<<dim3(256, B), 256, 0, stream>>>(
      S1f, s1_cw, s1_cb, s1_wx, XDS, SBf, L);
  // 4. fused scan1 (conv+dt recompute) -> y1 @ S2f
  scan_kernel<8><<<dim3(128, B), 512, 0, stream>>>(
      S1f, s1_cw, s1_cb, XDS, s1_wdt, s1_bdt, S1f + HALF, SBf,
      s1_alog, s1_dd, S2f, 128, L);
  // 5. out-proj1 + LN: A = y1 fp32 channel-major -> act_mid split @ S1u
  //    (xcpre1/z1 dead after scan1)
  lgemm_kernel<128, 2><<<dim3(512), 256, 0, stream>>>(
      S2f, (u16*)(WP + WOFFO1), WNO1, s1_lnw, s1_lnb,
      M, 128, S1u, AN1, nullptr, L);
  // 6. mid linear + silu -> act_lin split @ S2u (y1 dead after step 5)
  mgemm_kernel<1, 0><<<dim3(2, 256), 256, 0, stream>>>(
      S1u, AN1, nullptr, (u16*)(WP + WOFFL), WNL, lin_b, M, 256, 128,
      nullptr, nullptr, S2u, AN2, 0, L);
  // 7. stage2 in-proj -> xcpre2 @ S0f, z2 @ S1f
  mgemm_kernel<0, 0><<<dim3(4, 256), 256, 0, stream>>>(
      S2u, AN2, nullptr, (u16*)(WP + WOFF2), WN2, s2_bin, M, 512, 256,
      S0f, S1f, nullptr, 0, 256, L);
  // 8. proj2: xcpre2 -> xds @ XDS, B/C @ SBf
  proj_kernel<256, 16><<<dim3(256, B), 256, 0, stream>>>(
      S0f, s2_cw, s2_cb, s2_wx, XDS, SBf, L);
  // 9. fused scan2 -> y2 @ S2f (act_lin dead after step 7)
  scan_kernel<16><<<dim3(256, B), 512, 0, stream>>>(
      S0f, s2_cw, s2_cb, XDS, s2_wdt, s2_bdt, S1f, SBf,
      s2_alog, s2_dd, S2f, 256, L);
  // 10. out-proj2 + LN: A = y2 fp32 channel-major -> d_out fp32
  lgemm_kernel<256, 3><<<dim3(512), 256, 0, stream>>>(
      S2f, (u16*)(WP + WOFFO2), WNO2, s2_lnw, s2_lnb,
      M, 256, nullptr, 0, out, L);
}